// Round 13
// baseline (124.432 us; speedup 1.0000x reference)
//
#include <hip/hip_runtime.h>
#include <climits>

#define NB 8192
#define EPSQ 1e-8f

using i32x4  = __attribute__((ext_vector_type(4)))  int;
using i32x16 = __attribute__((ext_vector_type(16))) int;

// ---- ws layout (byte offsets) ----
// scalars F: 0 s0,1 sx1,2 sw1,3 sb1,4 sy1,5 sr1,6 sx2,7 sw2,8 sb2,9 sy2,10 sr2,11 sx3,12 swf,13 sb3,14 sy3
#define WS_F(ws)     ((float*)(ws))
#define WS_I(ws)     ((int*)((char*)(ws)+128))      // fallback atomics
#define WS_B1L(ws)   ((int*)((char*)(ws)+384))      // [16]
#define WS_B2L(ws)   ((int*)((char*)(ws)+448))      // [32]
#define WS_BFL(ws)   ((int*)((char*)(ws)+576))      // [16]
#define WS_M1F(ws)   ((float*)((char*)(ws)+640))    // [144]
#define WS_B1F(ws)   ((float*)((char*)(ws)+1280))   // [16] float bias levels (conv1)
#define WS_W1P(ws)   ((unsigned*)((char*)(ws)+1408)) // [48] conv1 weight rows packed i8x3 (dot4)
#define WS_B2FR(ws)  ((char*)(ws)+2048)             // [5][64][16] conv2 i8 B-fragments
#define WS_Q2TAB(ws) ((signed char*)((char*)(ws)+7168))  // [256] (fallback)
#define WS_Q3TAB(ws) ((signed char*)((char*)(ws)+7424))  // [256] (fallback)
#define WS_B1FR(ws)  ((char*)(ws)+7680)             // [64][16] conv1 i8 B-fragments (fallback)
#define WS_MFF(ws)   ((float*)((char*)(ws)+20480))  // [10][1568] float fc levels (fallback)
#define WS_WFP(ws)   ((char*)(ws)+83200)            // [49][64][16] fc i8 B-fragments
// per-block reduction slots (no atomics in full path)
#define WS_RA1(ws)   ((int*)((char*)(ws)+139264))   // [6272] conv1 amax
#define WS_RS1(ws)   ((int*)((char*)(ws)+164352))   // [6272] conv1 smax
#define WS_RA2(ws)   ((int*)((char*)(ws)+189440))   // [2048] conv2 amax
#define WS_RS2(ws)   ((int*)((char*)(ws)+197632))   // [2048] conv2 smax
#define WS_RA3(ws)   ((int*)((char*)(ws)+205824))   // [256]  fc amax
#define WS_RAX(ws)   ((float*)((char*)(ws)+206848)) // [2048] absx per-block max
#define WS_WMX(ws)   ((float*)((char*)(ws)+215040)) // [81] weight maxabs partials
#define WS_Q2B(ws)   ((signed char*)((char*)(ws)+215552)) // [65536] int16 pooled-I1 -> q2 level
#define WS_BIG_OFF   281600

__device__ __forceinline__ float clampf(float v, float lo, float hi){ return fminf(fmaxf(v, lo), hi); }

__device__ __forceinline__ int dot4(unsigned a, unsigned b, int c){
  return __builtin_amdgcn_sdot4((int)a, (int)b, c, false);
}

__device__ __forceinline__ float wave_max_f(float v){
#pragma unroll
  for (int off=32; off; off>>=1) v = fmaxf(v, __shfl_down(v, off, 64));
  return v;
}
__device__ __forceinline__ int wave_max_i(int v){
#pragma unroll
  for (int off=32; off; off>>=1) v = max(v, __shfl_down(v, off, 64));
  return v;
}

__device__ __forceinline__ void reduce2_atomic(int amax, int smax, int* gA, int* gS){
  amax = wave_max_i(amax); smax = wave_max_i(smax);
  __shared__ int sA[4], sS[4];
  int w = threadIdx.x>>6, l = threadIdx.x&63;
  if (l==0){ sA[w]=amax; sS[w]=smax; }
  __syncthreads();
  if (threadIdx.x==0){
#pragma unroll
    for (int i=1;i<4;i++){ amax=max(amax,sA[i]); smax=max(smax,sS[i]); }
    atomicMax(gA, amax); atomicMax(gS, smax);
  }
}

__device__ __forceinline__ void reduce2_store(int amax, int smax, int* pA, int* pS){
  amax = wave_max_i(amax); smax = wave_max_i(smax);
  __shared__ int sA[4], sS[4];
  int w = threadIdx.x>>6, l = threadIdx.x&63;
  if (l==0){ sA[w]=amax; sS[w]=smax; }
  __syncthreads();
  if (threadIdx.x==0){
#pragma unroll
    for (int i=1;i<4;i++){ amax=max(amax,sA[i]); smax=max(smax,sS[i]); }
    *pA = amax; *pS = smax;
  }
}

__global__ void k_init(char* ws){
  int* I = WS_I(ws);
  if (threadIdx.x==0){ I[0]=0; I[1]=0; I[2]=INT_MIN; I[3]=0; I[4]=INT_MIN; I[5]=0; }
}

// fallback absx
__global__ void k_absx(const float* __restrict__ x, char* ws){
  const float4* x4 = (const float4*)x;
  const int n4 = NB*784/4;
  float m = 0.f;
  for (int i = blockIdx.x*blockDim.x + threadIdx.x; i < n4; i += gridDim.x*blockDim.x){
    float4 v = x4[i];
    m = fmaxf(m, fmaxf(fmaxf(fabsf(v.x),fabsf(v.y)), fmaxf(fabsf(v.z),fabsf(v.w))));
  }
  m = wave_max_f(m);
  __shared__ float sm[4];
  int w = threadIdx.x>>6;
  if ((threadIdx.x&63)==0) sm[w]=m;
  __syncthreads();
  if (threadIdx.x==0){
    m = fmaxf(fmaxf(sm[0],sm[1]), fmaxf(sm[2],sm[3]));
    WS_RAX(ws)[blockIdx.x] = m;
  }
}

// full path: fused weight-max partials (blocks 0..80) + x-max partials (blocks 81..2128)
__global__ void k_absxw(const float* __restrict__ x,
                        const float* __restrict__ w1, const float* __restrict__ w2,
                        const float* __restrict__ wf, char* ws){
  __shared__ float red[256];
  int b = blockIdx.x, t = threadIdx.x;
  if (b < 81){
    float m = 0.f;
    if (b==0){ if (t<144) m = fabsf(w1[t]); }
    else if (b<19){ m = fabsf(w2[(b-1)*256 + t]); }
    else { int i=(b-19)*256+t; if (i<15680) m = fabsf(wf[i]); }
    red[t]=m; __syncthreads();
    for (int s=128;s;s>>=1){ if (t<s) red[t]=fmaxf(red[t],red[t+s]); __syncthreads(); }
    if (t==0) WS_WMX(ws)[b]=red[0];
    return;
  }
  const int xb = b - 81;                  // 0..2047
  const float4* x4 = (const float4*)x;
  const int n4 = NB*784/4;
  float m = 0.f;
  for (int i = xb*256 + t; i < n4; i += 2048*256){
    float4 v = x4[i];
    m = fmaxf(m, fmaxf(fmaxf(fabsf(v.x),fabsf(v.y)), fmaxf(fabsf(v.z),fabsf(v.w))));
  }
  m = wave_max_f(m);
  __shared__ float sm[4];
  int w = t>>6;
  if ((t&63)==0) sm[w]=m;
  __syncthreads();
  if (t==0){
    m = fmaxf(fmaxf(sm[0],sm[1]), fmaxf(sm[2],sm[3]));
    WS_RAX(ws)[xb] = m;
  }
}

// ---- shared reduce helpers (same loop order everywhere -> bit-identical) ----
__device__ __forceinline__ float red_wmx_range(char* ws, int lo, int n, float* red){
  int t = threadIdx.x;
  float m=0.f;
  if (t<n) m = WS_WMX(ws)[lo+t];
  red[t]=m; __syncthreads();
  for (int s=128;s;s>>=1){ if (t<s) red[t]=fmaxf(red[t],red[t+s]); __syncthreads(); }
  float r=red[0]; __syncthreads();
  return r;
}
__device__ __forceinline__ float red_rax(char* ws, float* red){
  int t = threadIdx.x;
  float mxv=0.f;
  for (int i=t;i<2048;i+=256) mxv=fmaxf(mxv,WS_RAX(ws)[i]);
  red[t]=mxv; __syncthreads();
  for (int s=128;s;s>>=1){ if (t<s) red[t]=fmaxf(red[t],red[t+s]); __syncthreads(); }
  float r=red[0]; __syncthreads();
  return r;
}

// full path: fused scales(block 0) + pack(blocks 1..282) + qx(blocks 283..)
__global__ void k_prep(const float* __restrict__ x,
                       const float* __restrict__ w1, const float* __restrict__ b1,
                       const float* __restrict__ w2, const float* __restrict__ wf,
                       char* __restrict__ ws, signed char* __restrict__ qx){
  __shared__ float red[256];
  const int b = blockIdx.x, t = threadIdx.x;
  if (b == 0){
    // exact k_scales body
    float vw1 = WS_WMX(ws)[0];
    float mw2 = red_wmx_range(ws, 1, 18, red);
    float mwf = red_wmx_range(ws, 19, 62, red);
    float mx  = red_rax(ws, red);
    float* F = WS_F(ws);
    float s0  = fmaxf(mx/127.f, EPSQ);
    float sx1 = fmaxf((127.f*s0)/127.f, EPSQ);
    float sw1 = fmaxf(vw1/7.f, EPSQ);
    float sw2 = fmaxf(mw2/7.f, EPSQ);
    float swf = fmaxf(mwf/7.f, EPSQ);
    float sb1 = sx1*sw1;
    if (t==0){ F[0]=s0; F[1]=sx1; F[2]=sw1; F[3]=sb1; F[7]=sw2; F[12]=swf; }
    if (t<144) WS_M1F(ws)[t] = clampf(rintf(w1[t]/sw1), -7.f, 7.f);
    if (t<16){
      int bl = (int)rintf(b1[t]/sb1);
      WS_B1L(ws)[t] = bl;
      WS_B1F(ws)[t] = (float)bl;
    }
    __syncthreads();
    if (t<48){
      int oc = t/3, row = t - oc*3;
      const float* m = WS_M1F(ws) + oc*9 + row*3;
      unsigned b0 = (unsigned)(unsigned char)(signed char)(int)m[0];
      unsigned bb1 = (unsigned)(unsigned char)(signed char)(int)m[1];
      unsigned b2c = (unsigned)(unsigned char)(signed char)(int)m[2];
      WS_W1P(ws)[t] = b0 | (bb1<<8) | (b2c<<16);
    }
    return;
  }
  if (b < 283){
    // pack block: derive sw1/sw2/swf locally from WMX (same order as block 0)
    float vw1 = WS_WMX(ws)[0];
    float mw2 = red_wmx_range(ws, 1, 18, red);
    float mwf = red_wmx_range(ws, 19, 62, red);
    float sw1 = fmaxf(vw1/7.f, EPSQ);
    float sw2 = fmaxf(mw2/7.f, EPSQ);
    float swf = fmaxf(mwf/7.f, EPSQ);
    int id = (b-1)*256 + t;
    if (id < 5120){
      int chunk=id>>10, r=id&1023, ln=r>>4, j=r&15;
      int tap=2*chunk+(ln>>5), oc=ln&31;
      signed char v=0;
      if (tap<9) v=(signed char)clampf(rintf(w2[oc*144 + j*9 + tap]/sw2), -7.f, 7.f);
      WS_B2FR(ws)[id]=v;
    } else if (id < 6144){
      int i=id-5120;
      int ln=i>>4, j=i&15;
      int k=(ln>>5)*16+j, oc=ln&31;
      signed char v=0;
      if (k<9 && oc<16) v=(signed char)clampf(rintf(w1[oc*9+k]/sw1), -7.f, 7.f);
      WS_B1FR(ws)[i]=v;
    } else if (id < 56320){
      int i=id-6144;
      int chunk=i>>10, r2=i&1023, ln=r2>>4, j=r2&15;
      int oc=ln&31, k=chunk*32+(ln>>5)*16+j;
      int cell=k>>5, ch=k&31;
      signed char v=0;
      if (oc<10) v=(signed char)clampf(rintf(wf[oc*1568 + ch*49 + cell]/swf), -7.f, 7.f);
      ((signed char*)WS_WFP(ws))[i]=v;
    } else if (id < 72000){
      int i=id-56320;
      WS_MFF(ws)[i] = clampf(rintf(wf[i]/swf), -7.f, 7.f);
    }
    return;
  }
  // qx block: derive s0 locally from RAX (same order as block 0)
  float mx = red_rax(ws, red);
  float s0 = fmaxf(mx/127.f, EPSQ);
  int id = (b-283)*256 + t;                 // < NB*240
  int img = id/240, w = id - img*240;
  int r = w>>3, c4 = (w&7)<<2;
  const float* xi = x + img*784;
  unsigned out = 0;
#pragma unroll
  for (int j=0;j<4;j++){
    int c = c4+j;
    bool valid = (r>=1) && (r<=28) && (c>=1) && (c<=28);
    int q = 0;
    if (valid){
      float xv = xi[(r-1)*28 + (c-1)];
      q = (int)clampf(rintf(xv/s0), -128.f, 127.f);
    }
    out |= ((unsigned)(unsigned char)(signed char)q) << (8*j);
  }
  ((unsigned*)qx)[id] = out;
}

// fallback: verified monolithic scale+pack kernel
__global__ void k_wq(const float* __restrict__ w1, const float* __restrict__ b1,
                     const float* __restrict__ w2, const float* __restrict__ wf,
                     char* ws){
  __shared__ float red[256];
  float* F = WS_F(ws);
  int t = threadIdx.x;
  auto bmaxabs = [&](const float* p, int n)->float{
    float m=0.f; for (int i=t;i<n;i+=256) m=fmaxf(m,fabsf(p[i]));
    red[t]=m; __syncthreads();
    for (int s=128;s;s>>=1){ if (t<s) red[t]=fmaxf(red[t],red[t+s]); __syncthreads(); }
    float r=red[0]; __syncthreads(); return r;
  };
  float mw1 = bmaxabs(w1,144);
  float mw2 = bmaxabs(w2,4608);
  float mwf = bmaxabs(wf,15680);
  float mxv=0.f;
  for (int i=t;i<2048;i+=256) mxv=fmaxf(mxv,WS_RAX(ws)[i]);
  red[t]=mxv; __syncthreads();
  for (int s=128;s;s>>=1){ if (t<s) red[t]=fmaxf(red[t],red[t+s]); __syncthreads(); }
  float mx=red[0]; __syncthreads();

  float s0  = fmaxf(mx/127.f, EPSQ);
  float sx1 = fmaxf((127.f*s0)/127.f, EPSQ);
  float sw1 = fmaxf(mw1/7.f, EPSQ);
  float sw2 = fmaxf(mw2/7.f, EPSQ);
  float swf = fmaxf(mwf/7.f, EPSQ);
  float sb1 = sx1*sw1;
  if (t==0){ F[0]=s0; F[1]=sx1; F[2]=sw1; F[3]=sb1; F[7]=sw2; F[12]=swf; }
  float* m1f = WS_M1F(ws);
  for (int i=t;i<144;i+=256) m1f[i] = clampf(rintf(w1[i]/sw1), -7.f, 7.f);
  if (t<16){
    int bl = (int)rintf(b1[t]/sb1);
    WS_B1L(ws)[t] = bl;
    WS_B1F(ws)[t] = (float)bl;
  }
  for (int i=t;i<5120;i+=256){
    int chunk=i>>10, r=i&1023, ln=r>>4, j=r&15;
    int tap=2*chunk+(ln>>5), oc=ln&31;
    signed char v=0;
    if (tap<9) v=(signed char)clampf(rintf(w2[oc*144 + j*9 + tap]/sw2), -7.f, 7.f);
    WS_B2FR(ws)[i]=v;
  }
  for (int i=t;i<1024;i+=256){
    int ln=i>>4, j=i&15;
    int k=(ln>>5)*16+j, oc=ln&31;
    signed char v=0;
    if (k<9 && oc<16) v=(signed char)clampf(rintf(w1[oc*9+k]/sw1), -7.f, 7.f);
    WS_B1FR(ws)[i]=v;
  }
  float* mff = WS_MFF(ws);
  for (int i=t;i<15680;i+=256) mff[i] = clampf(rintf(wf[i]/swf), -7.f, 7.f);
  for (int i=t;i<50176;i+=256){
    int chunk=i>>10, r2=i&1023, ln=r2>>4, j=r2&15;
    int oc=ln&31, k=chunk*32+(ln>>5)*16+j;
    int cell=k>>5, ch=k&31;
    signed char v=0;
    if (oc<10) v=(signed char)clampf(rintf(wf[oc*1568 + ch*49 + cell]/swf), -7.f, 7.f);
    ((signed char*)WS_WFP(ws))[i]=v;
  }
}

// fallback scale kernels
template<bool FULLR>
__global__ void k_s1(const float* __restrict__ b2, char* ws){
  float* F=WS_F(ws); int* I=WS_I(ws);
  __shared__ int rA[256], rS[256];
  __shared__ float sh[4];
  int t=threadIdx.x;
  int amaxI, smaxI;
  if constexpr (FULLR){
    int a=0, s=INT_MIN;
    const int* ra=WS_RA1(ws); const int* rs=WS_RS1(ws);
    for (int i=t;i<6272;i+=256){ a=max(a,ra[i]); s=max(s,rs[i]); }
    rA[t]=a; rS[t]=s; __syncthreads();
    for (int st=128;st;st>>=1){ if (t<st){ rA[t]=max(rA[t],rA[t+st]); rS[t]=max(rS[t],rS[t+st]); } __syncthreads(); }
    amaxI=rA[0]; smaxI=rS[0];
  } else { amaxI=I[1]; smaxI=I[2]; }
  if (t==0){
    float sb1=F[3];
    float sy1 = fmaxf((sb1*(float)amaxI)/127.f, EPSQ);
    float mp  = sb1*(float)smaxI;
    float P1  = clampf(rintf(mp/sy1), 0.f, 127.f);
    float sr1 = fmaxf((sy1*P1)/15.f, EPSQ);
    float N1  = clampf(rintf((sy1*P1)/sr1), 0.f, 15.f);
    float sx2 = fmaxf((N1*sr1)/127.f, EPSQ);
    float sb2 = sx2*F[7];
    F[4]=sy1; F[5]=sr1; F[6]=sx2; F[8]=sb2;
    sh[0]=sy1; sh[1]=sr1; sh[2]=sx2; sh[3]=sb2;
  }
  __syncthreads();
  float sy1=sh[0], sr1=sh[1], sx2=sh[2], sb2=sh[3];
  int k = t-128;
  float n = (k>0) ? clampf(rintf((sy1*(float)k)/sr1), 0.f, 15.f) : 0.f;
  WS_Q2TAB(ws)[t] = (signed char)clampf(rintf((n*sr1)/sx2), -128.f, 127.f);
  if (t<32) WS_B2L(ws)[t] = (int)rintf(b2[t]/sb2);
}

// full path: fused s1 + q2big (256 blocks, deterministic redundant reduce)
__global__ void k_s1q2(const float* __restrict__ b2, char* ws){
  float* F=WS_F(ws);
  __shared__ int rA[256], rS[256];
  int t=threadIdx.x;
  int a=0, s=INT_MIN;
  const int* ra=WS_RA1(ws); const int* rs=WS_RS1(ws);
  for (int i=t;i<6272;i+=256){ a=max(a,ra[i]); s=max(s,rs[i]); }
  rA[t]=a; rS[t]=s; __syncthreads();
  for (int st=128;st;st>>=1){ if (t<st){ rA[t]=max(rA[t],rA[t+st]); rS[t]=max(rS[t],rS[t+st]); } __syncthreads(); }
  int amaxI=rA[0], smaxI=rS[0];
  float sb1=F[3];
  float sy1 = fmaxf((sb1*(float)amaxI)/127.f, EPSQ);
  float P1  = clampf(rintf((sb1*(float)smaxI)/sy1), 0.f, 127.f);
  float sr1 = fmaxf((sy1*P1)/15.f, EPSQ);
  float N1  = clampf(rintf((sy1*P1)/sr1), 0.f, 15.f);
  float sx2 = fmaxf((N1*sr1)/127.f, EPSQ);
  float sb2 = sx2*F[7];
  if (blockIdx.x==0){
    if (t==0){ F[4]=sy1; F[5]=sr1; F[6]=sx2; F[8]=sb2; }
    if (t<32) WS_B2L(ws)[t] = (int)rintf(b2[t]/sb2);
  }
  int idx = blockIdx.x*256 + t;
  int m = idx - 32768;
  float k1 = clampf(rintf((sb1*(float)m)/sy1), -128.f, 127.f);
  float n  = (k1>0.f) ? clampf(rintf((sy1*k1)/sr1), 0.f, 15.f) : 0.f;
  WS_Q2B(ws)[idx] = (signed char)clampf(rintf((n*sr1)/sx2), -128.f, 127.f);
}

template<bool FULLR>
__global__ void k_s2(const float* __restrict__ bf, char* ws){
  float* F=WS_F(ws); int* I=WS_I(ws);
  __shared__ int rA[256], rS[256];
  __shared__ float sh[4];
  int t=threadIdx.x;
  int amaxI, smaxI;
  if constexpr (FULLR){
    int a=0, s=INT_MIN;
    const int* ra=WS_RA2(ws); const int* rs=WS_RS2(ws);
    for (int i=t;i<2048;i+=256){ a=max(a,ra[i]); s=max(s,rs[i]); }
    rA[t]=a; rS[t]=s; __syncthreads();
    for (int st=128;st;st>>=1){ if (t<st){ rA[t]=max(rA[t],rA[t+st]); rS[t]=max(rS[t],rS[t+st]); } __syncthreads(); }
    amaxI=rA[0]; smaxI=rS[0];
  } else { amaxI=I[3]; smaxI=I[4]; }
  if (t==0){
    float sb2=F[8];
    float sy2 = fmaxf((sb2*(float)amaxI)/127.f, EPSQ);
    float mp  = sb2*(float)smaxI;
    float P2  = clampf(rintf(mp/sy2), 0.f, 127.f);
    float sr2 = fmaxf((sy2*P2)/15.f, EPSQ);
    float N2  = clampf(rintf((sy2*P2)/sr2), 0.f, 15.f);
    float sx3 = fmaxf((N2*sr2)/127.f, EPSQ);
    float sb3 = sx3*F[12];
    F[9]=sy2; F[10]=sr2; F[11]=sx3; F[13]=sb3;
    sh[0]=sy2; sh[1]=sr2; sh[2]=sx3; sh[3]=sb3;
  }
  __syncthreads();
  float sy2=sh[0], sr2=sh[1], sx3=sh[2], sb3=sh[3];
  int k = t-128;
  float n = (k>0) ? clampf(rintf((sy2*(float)k)/sr2), 0.f, 15.f) : 0.f;
  WS_Q3TAB(ws)[t] = (signed char)clampf(rintf((n*sr2)/sx3), -128.f, 127.f);
  if (t<16) WS_BFL(ws)[t] = (t<10) ? (int)rintf(bf[t]/sb3) : 0;
}

template<bool FULLR>
__global__ void k_s3(char* ws){
  float* F=WS_F(ws); int* I=WS_I(ws);
  __shared__ int rA[256];
  int t=threadIdx.x;
  int amaxI;
  if constexpr (FULLR){
    rA[t] = WS_RA3(ws)[t];
    __syncthreads();
    for (int st=128;st;st>>=1){ if (t<st) rA[t]=max(rA[t],rA[t+st]); __syncthreads(); }
    amaxI = rA[0];
  } else { amaxI = I[5]; }
  if (t==0) F[14] = fmaxf((F[13]*(float)amaxI)/127.f, EPSQ);
}

// ================= FULL PATH compute =================
// P2b: conv1 via sdot4 + pool1 + per-block (amax,smax). 1 thread = 1 (img, pooled-cell).
__global__ __launch_bounds__(256) void k_conv1d(const signed char* __restrict__ qx,
                                                char* __restrict__ ws,
                                                short* __restrict__ i1p){
  const int t = threadIdx.x;
  const int id = blockIdx.x*256 + t;
  const int img = id/196, cell = id - img*196;
  const int py = cell/14, px = cell - py*14;
  const signed char* qb = qx + img*960 + (2*py)*32;
  const int pc0 = 2*px;
  const int al = pc0 & ~3, sh = (pc0&3)*8;
  unsigned wrd[4], whi[4];
#pragma unroll
  for (int rr=0; rr<4; rr++){
    unsigned lo = *(const unsigned*)(qb + rr*32 + al);
    unsigned hi = *(const unsigned*)(qb + rr*32 + al + 4);
    wrd[rr] = (unsigned)(((((unsigned long long)hi)<<32)|lo) >> sh);
    whi[rr] = wrd[rr] >> 8;
  }
  const unsigned* __restrict__ w1p = WS_W1P(ws);  // uniform -> s_load
  const int* __restrict__ b1l = WS_B1L(ws);
  int amax=0, smax=INT_MIN;
  short outv[16];
#pragma unroll
  for (int oc=0; oc<16; oc++){
    unsigned w0 = w1p[oc*3], w1 = w1p[oc*3+1], w2 = w1p[oc*3+2];
    int bl = b1l[oc];
    int a00 = dot4(wrd[2], w2, dot4(wrd[1], w1, dot4(wrd[0], w0, bl)));
    int a01 = dot4(whi[2], w2, dot4(whi[1], w1, dot4(whi[0], w0, bl)));
    int a10 = dot4(wrd[3], w2, dot4(wrd[2], w1, dot4(wrd[1], w0, bl)));
    int a11 = dot4(whi[3], w2, dot4(whi[2], w1, dot4(whi[1], w0, bl)));
    int mx = max(max(a00,a01), max(a10,a11));
    int ax = max(max(a00<0?-a00:a00, a01<0?-a01:a01), max(a10<0?-a10:a10, a11<0?-a11:a11));
    amax = max(amax, ax);
    smax = max(smax, mx);
    outv[oc] = (short)mx;
  }
  int4* dst = (int4*)(i1p + (size_t)id*16);
  dst[0] = *(const int4*)&outv[0];
  dst[1] = *(const int4*)&outv[8];
  reduce2_store(amax, smax, &WS_RA1(ws)[blockIdx.x], &WS_RS1(ws)[blockIdx.x]);
}

// P3: conv2 MFMA, pool-cell-grouped M-row permutation; requant via q2big table.
__global__ __launch_bounds__(256) void k_conv2r(char* __restrict__ ws,
                                                short* __restrict__ i1p,
                                                int* __restrict__ p2g){
  __shared__ __align__(16) signed char q2p4[4][4096];   // per-wave padded [16][16][16ch]
  const int t=threadIdx.x, lane=t&63, wid=t>>6;
  const int img = blockIdx.x*4 + wid;
  signed char* q2p = q2p4[wid];
  const signed char* __restrict__ q2b = WS_Q2B(ws);

#pragma unroll
  for (int k=0;k<8;k++) ((unsigned long long*)q2p)[lane + 64*k] = 0ULL;

  const unsigned* src = (const unsigned*)(i1p + (size_t)img*3136);
#pragma unroll
  for (int k=0;k<24;k++){
    int idx = lane + 64*k;
    unsigned wv = src[idx];
    int e0 = idx*2;
    int cellc = e0 >> 4, ch = e0 & 15;
    int pyc = cellc/14, pxc = cellc - pyc*14;
    int m0 = (int)(short)(wv & 0xFFFFu);
    int m1 = (int)(short)(wv >> 16);
    int b0 = (int)(unsigned char)q2b[m0+32768];
    int b1 = (int)(unsigned char)q2b[m1+32768];
    *(unsigned short*)(q2p + ((pyc+1)*16 + (pxc+1))*16 + ch) = (unsigned short)(b0 | (b1<<8));
  }
  if (lane < 32){
    int idx = 1536 + lane;
    unsigned wv = src[idx];
    int e0 = idx*2;
    int cellc = e0 >> 4, ch = e0 & 15;
    int pyc = cellc/14, pxc = cellc - pyc*14;
    int m0 = (int)(short)(wv & 0xFFFFu);
    int m1 = (int)(short)(wv >> 16);
    int b0 = (int)(unsigned char)q2b[m0+32768];
    int b1 = (int)(unsigned char)q2b[m1+32768];
    *(unsigned short*)(q2p + ((pyc+1)*16 + (pxc+1))*16 + ch) = (unsigned short)(b0 | (b1<<8));
  }

  i32x4 bfr[5];
  const i32x4* bg = (const i32x4*)WS_B2FR(ws);
#pragma unroll
  for (int c=0;c<5;c++) bfr[c] = bg[c*64+lane];
  const int col = lane&31, h = lane>>5;
  const int bias = WS_B2L(ws)[col];
  int amax2=0, smax2=INT_MIN;
  const int TOFF[9] = {0,1,2,16,17,18,32,33,34};
  int* dstb = p2g + (size_t)img*1568;

#pragma unroll
  for (int mt=0; mt<7; mt++){
    int m = mt*32 + col;
    int g = m>>2, sub = m&3;
    bool gv = g < 49;
    int py = (g*37)>>8;            // g/7, exact for g<56
    int px = g - py*7;
    int oy = 2*py + (sub>>1), ox = 2*px + (sub&1);
    int E0 = oy*16 + ox;
    i32x16 acc;
#pragma unroll
    for (int r=0;r<16;r++) acc[r] = bias;
#pragma unroll
    for (int c=0;c<5;c++){
      const int t0 = TOFF[2*c];
      const int t1 = (2*c+1<9) ? TOFF[2*c+1] : -1;
      int toff = h ? t1 : t0;
      int entry = (gv && toff>=0) ? (E0 + toff) : 0;   // entry 0 = zero border
      i32x4 a = *(const i32x4*)(q2p + entry*16);
      acc = __builtin_amdgcn_mfma_i32_32x32x32_i8(a, bfr[c], acc, 0,0,0);
    }
#pragma unroll
    for (int i=0;i<4;i++){
      int gg = mt*8 + 2*i + h;
      if (gg < 49){
        int v0=acc[4*i], v1=acc[4*i+1], v2=acc[4*i+2], v3=acc[4*i+3];
        int a0=v0<0?-v0:v0, a1=v1<0?-v1:v1, a2=v2<0?-v2:v2, a3=v3<0?-v3:v3;
        amax2 = max(amax2, max(max(a0,a1),max(a2,a3)));
        int mx = max(max(v0,v1),max(v2,v3));
        smax2 = max(smax2, mx);
        dstb[gg*32 + col] = mx;
      }
    }
  }
  reduce2_store(amax2, smax2, &WS_RA2(ws)[blockIdx.x], &WS_RS2(ws)[blockIdx.x]);
}

// P4: fused s2 + requant pooled-I2 -> q3 levels (12544 blocks, redundant deterministic reduce)
__global__ void k_rq2s(const float* __restrict__ bf, char* __restrict__ ws,
                       const int* __restrict__ p2g, signed char* __restrict__ q3g){
  float* F = WS_F(ws);
  __shared__ int rA[256], rS[256];
  __shared__ signed char q3t[256];
  int t=threadIdx.x;
  int a=0, s=INT_MIN;
  const int* ra=WS_RA2(ws); const int* rs=WS_RS2(ws);
  for (int i=t;i<2048;i+=256){ a=max(a,ra[i]); s=max(s,rs[i]); }
  rA[t]=a; rS[t]=s; __syncthreads();
  for (int st=128;st;st>>=1){ if (t<st){ rA[t]=max(rA[t],rA[t+st]); rS[t]=max(rS[t],rS[t+st]); } __syncthreads(); }
  int amaxI=rA[0], smaxI=rS[0];
  float sb2=F[8];
  float sy2 = fmaxf((sb2*(float)amaxI)/127.f, EPSQ);
  float P2  = clampf(rintf((sb2*(float)smaxI)/sy2), 0.f, 127.f);
  float sr2 = fmaxf((sy2*P2)/15.f, EPSQ);
  float N2  = clampf(rintf((sy2*P2)/sr2), 0.f, 15.f);
  float sx3 = fmaxf((N2*sr2)/127.f, EPSQ);
  float sb3 = sx3*F[12];
  if (blockIdx.x==0){
    if (t==0){ F[9]=sy2; F[10]=sr2; F[11]=sx3; F[13]=sb3; }
    if (t<16) WS_BFL(ws)[t] = (t<10) ? (int)rintf(bf[t]/sb3) : 0;
  }
  // per-block q3 table (identical formula as fallback k_s2)
  {
    int k = t-128;
    float n = (k>0) ? clampf(rintf((sy2*(float)k)/sr2), 0.f, 15.f) : 0.f;
    q3t[t] = (signed char)clampf(rintf((n*sr2)/sx3), -128.f, 127.f);
  }
  __syncthreads();
  int id = blockIdx.x*256 + t;
  i32x4 m4 = ((const i32x4*)p2g)[id];
  unsigned out=0;
#pragma unroll
  for (int j=0;j<4;j++){
    float k2 = clampf(rintf((sb2*(float)m4[j])/sy2), -128.f, 127.f);
    out |= ((unsigned)(unsigned char)q3t[(int)k2+128]) << (8*j);
  }
  ((unsigned*)q3g)[id] = out;
}

// P5: fc as i8 MFMA GEMM, 256 blocks, K split across 4 waves (unrolled), LDS combine.
__global__ __launch_bounds__(256) void k_fc(char* __restrict__ ws,
                                            const signed char* __restrict__ q3g,
                                            int* __restrict__ i3out){
  __shared__ int part[3][16][64];
  int t=threadIdx.x, lane=t&63, wid=t>>6;
  int mt = blockIdx.x;              // 0..255
  const int col=lane&31, h=lane>>5;
  const signed char* A0 = q3g + (size_t)(mt*32 + col)*1568 + 16*h;
  const i32x4* wfp = (const i32x4*)WS_WFP(ws);
  i32x16 acc;
#pragma unroll
  for (int r=0;r<16;r++) acc[r]=0;
#pragma unroll
  for (int cc=0; cc<13; cc++){
    int c = wid + cc*4;
    if (c < 49){
      i32x4 a = *(const i32x4*)(A0 + c*32);
      i32x4 b = wfp[c*64 + lane];
      acc = __builtin_amdgcn_mfma_i32_32x32x32_i8(a, b, acc, 0,0,0);
    }
  }
  if (wid>0){
#pragma unroll
    for (int r=0;r<16;r++) part[wid-1][r][lane] = acc[r];
  }
  __syncthreads();
  if (wid==0){
    int bias = (col<10) ? WS_BFL(ws)[col] : 0;
    int am=0;
#pragma unroll
    for (int r=0;r<16;r++){
      int v = acc[r] + part[0][r][lane] + part[1][r][lane] + part[2][r][lane] + bias;
      int row=(r&3)+8*(r>>2)+4*h;
      int img = mt*32+row;
      if (col<10){
        i3out[img*10+col] = v;
        am = max(am, v<0?-v:v);
      }
    }
    am = wave_max_i(am);
    if (lane==0) WS_RA3(ws)[blockIdx.x] = am;
  }
}

// full-path output: inline RA3 reduce (deterministic, identical in every block)
__global__ void k_out2(char* __restrict__ ws, float* __restrict__ out){
  __shared__ int rA[256];
  int t=threadIdx.x;
  rA[t] = WS_RA3(ws)[t];
  __syncthreads();
  for (int st=128;st;st>>=1){ if (t<st) rA[t]=max(rA[t],rA[t+st]); __syncthreads(); }
  float sb3 = WS_F(ws)[13];
  float sy3 = fmaxf((sb3*(float)rA[0])/127.f, EPSQ);
  int i = blockIdx.x*256 + t;
  if (i < NB*10){
    int iv = ((const int*)out)[i];
    float y = sb3*(float)iv;
    float q = clampf(rintf(y/sy3), -128.f, 127.f);
    out[i] = q*sy3;
  }
}

// ================= FALLBACK (verified) =================
__global__ __launch_bounds__(256) void k_c1(const float* __restrict__ x, char* __restrict__ ws,
                                            short* __restrict__ i1p){
  constexpr int OFF_K0=0, OFF_A=960, OFF_I1=13760, OFF_B1=38848;
  __shared__ __align__(16) char arena[38912];
  signed char* k0b = (signed char*)(arena+OFF_K0);
  signed char* Abuf= (signed char*)(arena+OFF_A);
  short*       I1s = (short*)(arena+OFF_I1);
  int*         b1i = (int*)(arena+OFF_B1);

  const int tid=threadIdx.x, img=blockIdx.x;
  const int lane=tid&63, wid=tid>>6;
  const float s0 = WS_F(ws)[0];

  if (tid<16) b1i[tid]=WS_B1L(ws)[tid];
  for (int i=tid;i<240;i+=256) ((int*)k0b)[i]=0;
  for (int i=tid;i<3200;i+=256) ((int*)Abuf)[i]=0;
  __syncthreads();
  const float* xi = x + img*784;
  for (int i=tid;i<784;i+=256){
    int r=i/28, c=i-r*28;
    float v = clampf(rintf(xi[i]/s0), -128.f, 127.f);
    k0b[(r+1)*32 + (c+1)] = (signed char)v;
  }
  __syncthreads();
  for (int p=tid;p<784;p+=256){
    int oy=p/28, ox=p-oy*28;
    int base = oy*32+ox;
    int al = base & ~3, sh = (base&3)*8;
    unsigned l0a=*(const unsigned*)(k0b+al),    l1a=*(const unsigned*)(k0b+al+4);
    unsigned l0b=*(const unsigned*)(k0b+al+32), l1b=*(const unsigned*)(k0b+al+36);
    unsigned l0c=*(const unsigned*)(k0b+al+64), l1c=*(const unsigned*)(k0b+al+68);
    unsigned u0=(unsigned)(((((unsigned long long)l1a)<<32)|l0a)>>sh);
    unsigned u1=(unsigned)(((((unsigned long long)l1b)<<32)|l0b)>>sh);
    unsigned u2=(unsigned)(((((unsigned long long)l1c)<<32)|l0c)>>sh);
    i32x4 row;
    row[0]=(int)((u0&0xFFFFFFu)|(u1<<24));
    row[1]=(int)(((u1>>8)&0xFFFFu)|((u2&0xFFFFu)<<16));
    row[2]=(int)((u2>>16)&0xFFu);
    row[3]=0;
    *(i32x4*)(Abuf + p*16) = row;
  }
  __syncthreads();
  const i32x4 bfr = ((const i32x4*)WS_B1FR(ws))[lane];
  const int col=lane&31, h=lane>>5;
  const int bias=(col<16)? b1i[col] : 0;
  int amax=0, smax=INT_MIN;
  for (int mt=wid; mt<25; mt+=4){
    i32x4 a={0,0,0,0};
    if (h==0) a = *(const i32x4*)(Abuf + (mt*32+col)*16);
    i32x16 acc;
#pragma unroll
    for (int r=0;r<16;r++) acc[r]=bias;
    acc=__builtin_amdgcn_mfma_i32_32x32x32_i8(a,bfr,acc,0,0,0);
#pragma unroll
    for (int r=0;r<16;r++){
      int row=(r&3)+8*(r>>2)+4*h;
      int p=mt*32+row;
      if (p<784 && col<16){
        int v=acc[r];
        amax=max(amax,v<0?-v:v); smax=max(smax,v);
        I1s[p*16+col]=(short)v;
      }
    }
  }
  __syncthreads();
  for (int i=tid;i<3136;i+=256){
    int pp=i>>4, c=i&15, py=pp/14, px=pp-py*14;
    int p0=py*56+px*2;
    int m=max(max((int)I1s[p0*16+c],(int)I1s[(p0+1)*16+c]),
              max((int)I1s[(p0+28)*16+c],(int)I1s[(p0+29)*16+c]));
    i1p[(size_t)img*3136 + i]=(short)m;
  }
  reduce2_atomic(amax,smax,&WS_I(ws)[1],&WS_I(ws)[2]);
}

template<bool FIN>
__global__ __launch_bounds__(256) void k_c2(char* __restrict__ ws, const short* __restrict__ i1p,
                                            int* __restrict__ i3out){
  constexpr int OFF_Q2L=0, OFF_B2I=3136, OFF_Q2T=3264, OFF_N2=3520,
                OFF_Q3T=9792, OFF_BFS=10048, OFF_Q3F=10112, OFF_RED=16384;
  constexpr int ARENA = FIN ? 16544 : 3520;
  __shared__ __align__(16) char arena[ARENA];
  signed char* q2l=(signed char*)(arena+OFF_Q2L);
  int* b2li=(int*)(arena+OFF_B2I);
  signed char* q2t=(signed char*)(arena+OFF_Q2T);

  const int tid=threadIdx.x, img=blockIdx.x;
  const int lane=tid&63, wid=tid>>6;
  const float* F=WS_F(ws);
  const float sb1=F[3], sy1=F[4];

  q2t[tid]=WS_Q2TAB(ws)[tid];
  if (tid<32) b2li[tid]=WS_B2L(ws)[tid];
  if constexpr (FIN){
    ((signed char*)(arena+OFF_Q3T))[tid]=WS_Q3TAB(ws)[tid];
    if (tid<16) ((int*)(arena+OFF_BFS))[tid]=WS_BFL(ws)[tid];
  }
  __syncthreads();
  for (int i=tid;i<3136;i+=256){
    int m=(int)i1p[(size_t)img*3136+i];
    float k1=clampf(rintf((sb1*(float)m)/sy1),-128.f,127.f);
    q2l[i]=q2t[(int)k1+128];
  }
  __syncthreads();

  i32x4 bfr[5];
  {
    const i32x4* bg=(const i32x4*)WS_B2FR(ws);
#pragma unroll
    for (int c=0;c<5;c++) bfr[c]=bg[c*64+lane];
  }
  const int col=lane&31, h=lane>>5;
  const int bias=b2li[col];
  int amax2=0, smax2=INT_MIN;
  float sb2=0.f, sy2=0.f;
  signed char* n2buf=nullptr;
  if constexpr (FIN){ sb2=F[8]; sy2=F[9]; n2buf=(signed char*)(arena+OFF_N2); }

  for (int mt=wid; mt<7; mt+=4){
    const int p=mt*32+col;
    const bool pv=p<196;
    const int oy=p/14, ox=p-oy*14;
    i32x16 acc;
#pragma unroll
    for (int r=0;r<16;r++) acc[r]=bias;
#pragma unroll
    for (int c=0;c<5;c++){
      const int tap=2*c+h;
      i32x4 a={0,0,0,0};
      if (pv && tap<9){
        const int iy=oy+tap/3-1, ix=ox+tap-(tap/3)*3-1;
        if ((unsigned)iy<14u && (unsigned)ix<14u) a=*(const i32x4*)(q2l+(iy*14+ix)*16);
      }
      acc=__builtin_amdgcn_mfma_i32_32x32x32_i8(a,bfr[c],acc,0,0,0);
    }
#pragma unroll
    for (int r=0;r<16;r++){
      const int row=(r&3)+8*(r>>2)+4*h;
      const int pp=mt*32+row;
      if (pp<196){
        const int v=acc[r];
        if constexpr (!FIN){ amax2=max(amax2,v<0?-v:v); smax2=max(smax2,v); }
        else {
          n2buf[col*196+pp]=(signed char)clampf(rintf((sb2*(float)v)/sy2),-128.f,127.f);
        }
      }
    }
  }
  if constexpr (!FIN){
    reduce2_atomic(amax2,smax2,&WS_I(ws)[3],&WS_I(ws)[4]);
    return;
  } else {
    __syncthreads();
    signed char* q3t_s=(signed char*)(arena+OFF_Q3T);
    float* q3f=(float*)(arena+OFF_Q3F);
    for (int i=tid;i<1568;i+=256){
      int cch=i/49, s=i-cch*49, qy=s/7, qx=s-qy*7;
      int b=cch*196+qy*28+qx*2;
      int m=max(max((int)n2buf[b],(int)n2buf[b+1]),max((int)n2buf[b+14],(int)n2buf[b+15]));
      q3f[i]=(float)q3t_s[m+128];
    }
    __syncthreads();
    const float* mff=WS_MFF(ws);
    float a10[10];
#pragma unroll
    for (int o=0;o<10;o++) a10[o]=0.f;
    for (int k=tid;k<1568;k+=256){
      float qa=q3f[k];
#pragma unroll
      for (int o=0;o<10;o++) a10[o]=fmaf(qa,mff[o*1568+k],a10[o]);
    }
#pragma unroll
    for (int o=0;o<10;o++){
#pragma unroll
      for (int off=32;off;off>>=1) a10[o]+=__shfl_down(a10[o],off,64);
    }
    float* redf=(float*)(arena+OFF_RED);
    int* bfs=(int*)(arena+OFF_BFS);
    if (lane==0){
#pragma unroll
      for (int o=0;o<10;o++) redf[wid*10+o]=a10[o];
    }
    __syncthreads();
    if (tid<10){
      float s=redf[tid]+redf[10+tid]+redf[20+tid]+redf[30+tid];
      int I3v=(int)s+bfs[tid];
      i3out[img*10+tid]=I3v;
      redf[tid]=(float)(I3v<0?-I3v:I3v);
    }
    __syncthreads();
    if (tid==0){
      int m=0;
#pragma unroll
      for (int o=0;o<10;o++) m=max(m,(int)redf[o]);
      atomicMax(&WS_I(ws)[5],m);
    }
  }
}

__global__ void k_out(char* ws, float* __restrict__ out){
  float* F=WS_F(ws);
  float sb3=F[13], sy3=F[14];
  int i = blockIdx.x*blockDim.x + threadIdx.x;
  if (i < NB*10){
    int iv = ((const int*)out)[i];
    float y = sb3*(float)iv;
    float q = clampf(rintf(y/sy3), -128.f, 127.f);
    out[i] = q*sy3;
  }
}

extern "C" void kernel_launch(void* const* d_in, const int* in_sizes, int n_in,
                              void* d_out, int out_size, void* d_ws, size_t ws_size,
                              hipStream_t stream){
  const float* x  = (const float*)d_in[0];
  const float* w1 = (const float*)d_in[1];
  const float* b1 = (const float*)d_in[2];
  const float* w2 = (const float*)d_in[3];
  const float* b2 = (const float*)d_in[4];
  const float* wf = (const float*)d_in[5];
  const float* bf = (const float*)d_in[6];
  char* ws = (char*)d_ws;
  float* out = (float*)d_out;
  int* i3 = (int*)d_out;

  const size_t QX_SZ  = (size_t)NB*960;
  const size_t I1_SZ  = (size_t)NB*6272;
  const size_t Q3_SZ  = (size_t)NB*1568;
  const size_t needFull = (size_t)WS_BIG_OFF + QX_SZ + I1_SZ + Q3_SZ;

  if (ws_size >= needFull){
    signed char* qx  = (signed char*)(ws + WS_BIG_OFF);
    short*       i1p = (short*)(ws + WS_BIG_OFF + QX_SZ);
    int*         p2g = (int*)i1p;
    signed char* q3g = (signed char*)(ws + WS_BIG_OFF + QX_SZ + I1_SZ);
    k_absxw <<<dim3(2129), dim3(256), 0, stream>>>(x, w1, w2, wf, ws);
    k_prep  <<<dim3(283 + NB*240/256), dim3(256), 0, stream>>>(x, w1, b1, w2, wf, ws, qx);
    k_conv1d<<<dim3(NB*196/256), dim3(256), 0, stream>>>(qx, ws, i1p);
    k_s1q2  <<<dim3(256), dim3(256), 0, stream>>>(b2, ws);
    k_conv2r<<<dim3(NB/4), dim3(256), 0, stream>>>(ws, i1p, p2g);
    k_rq2s  <<<dim3(NB*1568/1024), dim3(256), 0, stream>>>(bf, ws, p2g, q3g);
    k_fc    <<<dim3(256), dim3(256), 0, stream>>>(ws, q3g, i3);
    k_out2  <<<dim3((NB*10+255)/256), dim3(256), 0, stream>>>(ws, out);
  } else {
    short* i1p = (short*)(ws + WS_BIG_OFF);
    k_init<<<dim3(1), dim3(64), 0, stream>>>(ws);
    k_absx<<<dim3(2048), dim3(256), 0, stream>>>(x, ws);
    k_wq  <<<dim3(1), dim3(256), 0, stream>>>(w1, b1, w2, wf, ws);
    k_c1<<<dim3(NB), dim3(256), 0, stream>>>(x, ws, i1p);
    k_s1<false><<<dim3(1), dim3(256), 0, stream>>>(b2, ws);
    k_c2<false><<<dim3(NB), dim3(256), 0, stream>>>(ws, i1p, i3);
    k_s2<false><<<dim3(1), dim3(256), 0, stream>>>(bf, ws);
    k_c2<true ><<<dim3(NB), dim3(256), 0, stream>>>(ws, i1p, i3);
    k_s3<false><<<dim3(1), dim3(256), 0, stream>>>(ws);
    k_out<<<dim3((NB*10+255)/256), dim3(256), 0, stream>>>(ws, out);
  }
}

// Round 14
// 118.795 us; speedup vs baseline: 1.0474x; 1.0474x over previous
//
#include <hip/hip_runtime.h>
#include <climits>

#define NB 8192
#define EPSQ 1e-8f

using i32x4  = __attribute__((ext_vector_type(4)))  int;
using i32x16 = __attribute__((ext_vector_type(16))) int;

// ---- ws layout (byte offsets) ----
// scalars F: 0 s0,1 sx1,2 sw1,3 sb1,4 sy1,5 sr1,6 sx2,7 sw2,8 sb2,9 sy2,10 sr2,11 sx3,12 swf,13 sb3,14 sy3
#define WS_F(ws)     ((float*)(ws))
#define WS_I(ws)     ((int*)((char*)(ws)+128))      // fallback atomics
#define WS_B1L(ws)   ((int*)((char*)(ws)+384))      // [16]
#define WS_B2L(ws)   ((int*)((char*)(ws)+448))      // [32]
#define WS_BFL(ws)   ((int*)((char*)(ws)+576))      // [16]
#define WS_M1F(ws)   ((float*)((char*)(ws)+640))    // [144]
#define WS_B1F(ws)   ((float*)((char*)(ws)+1280))   // [16] float bias levels (conv1)
#define WS_W1P(ws)   ((unsigned*)((char*)(ws)+1408)) // [48] conv1 weight rows packed i8x3 (dot4)
#define WS_B2FR(ws)  ((char*)(ws)+2048)             // [5][64][16] conv2 i8 B-fragments
#define WS_Q2TAB(ws) ((signed char*)((char*)(ws)+7168))  // [256] (fallback)
#define WS_Q3TAB(ws) ((signed char*)((char*)(ws)+7424))  // [256]
#define WS_B1FR(ws)  ((char*)(ws)+7680)             // [64][16] conv1 i8 B-fragments (fallback)
#define WS_MFF(ws)   ((float*)((char*)(ws)+20480))  // [10][1568] float fc levels (fallback)
#define WS_WFP(ws)   ((char*)(ws)+83200)            // [49][64][16] fc i8 B-fragments
// per-block reduction slots (no atomics in full path)
#define WS_RA1(ws)   ((int*)((char*)(ws)+139264))   // [6272] conv1 amax
#define WS_RS1(ws)   ((int*)((char*)(ws)+164352))   // [6272] conv1 smax
#define WS_RA2(ws)   ((int*)((char*)(ws)+189440))   // [2048] conv2 amax
#define WS_RS2(ws)   ((int*)((char*)(ws)+197632))   // [2048] conv2 smax
#define WS_RA3(ws)   ((int*)((char*)(ws)+205824))   // [256]  fc amax
#define WS_RAX(ws)   ((float*)((char*)(ws)+206848)) // [2048] absx per-block max
#define WS_WMX(ws)   ((float*)((char*)(ws)+215040)) // [81] weight maxabs partials
#define WS_Q2B(ws)   ((signed char*)((char*)(ws)+215552)) // [65536] int16 pooled-I1 -> q2 level
#define WS_BIG_OFF   281600

__device__ __forceinline__ float clampf(float v, float lo, float hi){ return fminf(fmaxf(v, lo), hi); }

__device__ __forceinline__ int dot4(unsigned a, unsigned b, int c){
  return __builtin_amdgcn_sdot4((int)a, (int)b, c, false);
}

__device__ __forceinline__ float wave_max_f(float v){
#pragma unroll
  for (int off=32; off; off>>=1) v = fmaxf(v, __shfl_down(v, off, 64));
  return v;
}
__device__ __forceinline__ int wave_max_i(int v){
#pragma unroll
  for (int off=32; off; off>>=1) v = max(v, __shfl_down(v, off, 64));
  return v;
}

__device__ __forceinline__ void reduce2_atomic(int amax, int smax, int* gA, int* gS){
  amax = wave_max_i(amax); smax = wave_max_i(smax);
  __shared__ int sA[4], sS[4];
  int w = threadIdx.x>>6, l = threadIdx.x&63;
  if (l==0){ sA[w]=amax; sS[w]=smax; }
  __syncthreads();
  if (threadIdx.x==0){
#pragma unroll
    for (int i=1;i<4;i++){ amax=max(amax,sA[i]); smax=max(smax,sS[i]); }
    atomicMax(gA, amax); atomicMax(gS, smax);
  }
}

__device__ __forceinline__ void reduce2_store(int amax, int smax, int* pA, int* pS){
  amax = wave_max_i(amax); smax = wave_max_i(smax);
  __shared__ int sA[4], sS[4];
  int w = threadIdx.x>>6, l = threadIdx.x&63;
  if (l==0){ sA[w]=amax; sS[w]=smax; }
  __syncthreads();
  if (threadIdx.x==0){
#pragma unroll
    for (int i=1;i<4;i++){ amax=max(amax,sA[i]); smax=max(smax,sS[i]); }
    *pA = amax; *pS = smax;
  }
}

__global__ void k_init(char* ws){
  int* I = WS_I(ws);
  if (threadIdx.x==0){ I[0]=0; I[1]=0; I[2]=INT_MIN; I[3]=0; I[4]=INT_MIN; I[5]=0; }
}

// fallback absx
__global__ void k_absx(const float* __restrict__ x, char* ws){
  const float4* x4 = (const float4*)x;
  const int n4 = NB*784/4;
  float m = 0.f;
  for (int i = blockIdx.x*blockDim.x + threadIdx.x; i < n4; i += gridDim.x*blockDim.x){
    float4 v = x4[i];
    m = fmaxf(m, fmaxf(fmaxf(fabsf(v.x),fabsf(v.y)), fmaxf(fabsf(v.z),fabsf(v.w))));
  }
  m = wave_max_f(m);
  __shared__ float sm[4];
  int w = threadIdx.x>>6;
  if ((threadIdx.x&63)==0) sm[w]=m;
  __syncthreads();
  if (threadIdx.x==0){
    m = fmaxf(fmaxf(sm[0],sm[1]), fmaxf(sm[2],sm[3]));
    WS_RAX(ws)[blockIdx.x] = m;
  }
}

// full path: fused weight-max partials (blocks 0..80) + x-max partials (blocks 81..2128)
__global__ void k_absxw(const float* __restrict__ x,
                        const float* __restrict__ w1, const float* __restrict__ w2,
                        const float* __restrict__ wf, char* ws){
  __shared__ float red[256];
  int b = blockIdx.x, t = threadIdx.x;
  if (b < 81){
    float m = 0.f;
    if (b==0){ if (t<144) m = fabsf(w1[t]); }
    else if (b<19){ m = fabsf(w2[(b-1)*256 + t]); }
    else { int i=(b-19)*256+t; if (i<15680) m = fabsf(wf[i]); }
    red[t]=m; __syncthreads();
    for (int s=128;s;s>>=1){ if (t<s) red[t]=fmaxf(red[t],red[t+s]); __syncthreads(); }
    if (t==0) WS_WMX(ws)[b]=red[0];
    return;
  }
  const int xb = b - 81;                  // 0..2047
  const float4* x4 = (const float4*)x;
  const int n4 = NB*784/4;
  float m = 0.f;
  for (int i = xb*256 + t; i < n4; i += 2048*256){
    float4 v = x4[i];
    m = fmaxf(m, fmaxf(fmaxf(fabsf(v.x),fabsf(v.y)), fmaxf(fabsf(v.z),fabsf(v.w))));
  }
  m = wave_max_f(m);
  __shared__ float sm[4];
  int w = t>>6;
  if ((t&63)==0) sm[w]=m;
  __syncthreads();
  if (t==0){
    m = fmaxf(fmaxf(sm[0],sm[1]), fmaxf(sm[2],sm[3]));
    WS_RAX(ws)[xb] = m;
  }
}

// fallback weight-max (kept for structure parity; unused in full path)
__global__ void k_wmax(const float* __restrict__ w1, const float* __restrict__ w2,
                       const float* __restrict__ wf, char* ws){
  __shared__ float red[256];
  int b = blockIdx.x, t = threadIdx.x;
  float m = 0.f;
  if (b==0){ if (t<144) m = fabsf(w1[t]); }
  else if (b<19){ m = fabsf(w2[(b-1)*256 + t]); }
  else { int i=(b-19)*256+t; if (i<15680) m = fabsf(wf[i]); }
  red[t]=m; __syncthreads();
  for (int s=128;s;s>>=1){ if (t<s) red[t]=fmaxf(red[t],red[t+s]); __syncthreads(); }
  if (t==0) WS_WMX(ws)[b]=red[0];
}

// full path: reduce partials -> all scale scalars + conv1 weight/bias levels + packed dot4 rows
__global__ void k_scales(const float* __restrict__ w1, const float* __restrict__ b1, char* ws){
  __shared__ float red[256];
  float* F = WS_F(ws);
  int t = threadIdx.x;
  float vw1 = WS_WMX(ws)[0];
  float m2=0.f, mf=0.f;
  if (t<18) m2 = WS_WMX(ws)[1+t];
  if (t<62) mf = WS_WMX(ws)[19+t];
  red[t]=m2; __syncthreads();
  for (int s=128;s;s>>=1){ if (t<s) red[t]=fmaxf(red[t],red[t+s]); __syncthreads(); }
  float mw2=red[0]; __syncthreads();
  red[t]=mf; __syncthreads();
  for (int s=128;s;s>>=1){ if (t<s) red[t]=fmaxf(red[t],red[t+s]); __syncthreads(); }
  float mwf=red[0]; __syncthreads();
  float mxv=0.f;
  for (int i=t;i<2048;i+=256) mxv=fmaxf(mxv,WS_RAX(ws)[i]);
  red[t]=mxv; __syncthreads();
  for (int s=128;s;s>>=1){ if (t<s) red[t]=fmaxf(red[t],red[t+s]); __syncthreads(); }
  float mx=red[0]; __syncthreads();

  float s0  = fmaxf(mx/127.f, EPSQ);
  float sx1 = fmaxf((127.f*s0)/127.f, EPSQ);
  float sw1 = fmaxf(vw1/7.f, EPSQ);
  float sw2 = fmaxf(mw2/7.f, EPSQ);
  float swf = fmaxf(mwf/7.f, EPSQ);
  float sb1 = sx1*sw1;
  if (t==0){ F[0]=s0; F[1]=sx1; F[2]=sw1; F[3]=sb1; F[7]=sw2; F[12]=swf; }
  if (t<144) WS_M1F(ws)[t] = clampf(rintf(w1[t]/sw1), -7.f, 7.f);
  if (t<16){
    int bl = (int)rintf(b1[t]/sb1);
    WS_B1L(ws)[t] = bl;
    WS_B1F(ws)[t] = (float)bl;
  }
  __syncthreads();
  if (t<48){
    int oc = t/3, row = t - oc*3;
    const float* m = WS_M1F(ws) + oc*9 + row*3;
    unsigned b0 = (unsigned)(unsigned char)(signed char)(int)m[0];
    unsigned bb1 = (unsigned)(unsigned char)(signed char)(int)m[1];
    unsigned b2c = (unsigned)(unsigned char)(signed char)(int)m[2];
    WS_W1P(ws)[t] = b0 | (bb1<<8) | (b2c<<16);
  }
}

// full path: all fragment packing, one element/thread (282 blocks)
__global__ void k_pack(const float* __restrict__ w1, const float* __restrict__ w2,
                       const float* __restrict__ wf, char* ws){
  const float* F = WS_F(ws);
  int id = blockIdx.x*256 + threadIdx.x;
  if (id < 5120){
    float sw2 = F[7];
    int chunk=id>>10, r=id&1023, ln=r>>4, j=r&15;
    int tap=2*chunk+(ln>>5), oc=ln&31;
    signed char v=0;
    if (tap<9) v=(signed char)clampf(rintf(w2[oc*144 + j*9 + tap]/sw2), -7.f, 7.f);
    WS_B2FR(ws)[id]=v;
  } else if (id < 6144){
    float sw1 = F[2];
    int i=id-5120;
    int ln=i>>4, j=i&15;
    int k=(ln>>5)*16+j, oc=ln&31;
    signed char v=0;
    if (k<9 && oc<16) v=(signed char)clampf(rintf(w1[oc*9+k]/sw1), -7.f, 7.f);
    WS_B1FR(ws)[i]=v;
  } else if (id < 56320){
    float swf = F[12];
    int i=id-6144;
    int chunk=i>>10, r2=i&1023, ln=r2>>4, j=r2&15;
    int oc=ln&31, k=chunk*32+(ln>>5)*16+j;
    int cell=k>>5, ch=k&31;
    signed char v=0;
    if (oc<10) v=(signed char)clampf(rintf(wf[oc*1568 + ch*49 + cell]/swf), -7.f, 7.f);
    ((signed char*)WS_WFP(ws))[i]=v;
  } else if (id < 72000){
    float swf = F[12];
    int i=id-56320;
    WS_MFF(ws)[i] = clampf(rintf(wf[i]/swf), -7.f, 7.f);
  }
}

// fallback: verified monolithic scale+pack kernel
__global__ void k_wq(const float* __restrict__ w1, const float* __restrict__ b1,
                     const float* __restrict__ w2, const float* __restrict__ wf,
                     char* ws){
  __shared__ float red[256];
  float* F = WS_F(ws);
  int t = threadIdx.x;
  auto bmaxabs = [&](const float* p, int n)->float{
    float m=0.f; for (int i=t;i<n;i+=256) m=fmaxf(m,fabsf(p[i]));
    red[t]=m; __syncthreads();
    for (int s=128;s;s>>=1){ if (t<s) red[t]=fmaxf(red[t],red[t+s]); __syncthreads(); }
    float r=red[0]; __syncthreads(); return r;
  };
  float mw1 = bmaxabs(w1,144);
  float mw2 = bmaxabs(w2,4608);
  float mwf = bmaxabs(wf,15680);
  float mxv=0.f;
  for (int i=t;i<2048;i+=256) mxv=fmaxf(mxv,WS_RAX(ws)[i]);
  red[t]=mxv; __syncthreads();
  for (int s=128;s;s>>=1){ if (t<s) red[t]=fmaxf(red[t],red[t+s]); __syncthreads(); }
  float mx=red[0]; __syncthreads();

  float s0  = fmaxf(mx/127.f, EPSQ);
  float sx1 = fmaxf((127.f*s0)/127.f, EPSQ);
  float sw1 = fmaxf(mw1/7.f, EPSQ);
  float sw2 = fmaxf(mw2/7.f, EPSQ);
  float swf = fmaxf(mwf/7.f, EPSQ);
  float sb1 = sx1*sw1;
  if (t==0){ F[0]=s0; F[1]=sx1; F[2]=sw1; F[3]=sb1; F[7]=sw2; F[12]=swf; }
  float* m1f = WS_M1F(ws);
  for (int i=t;i<144;i+=256) m1f[i] = clampf(rintf(w1[i]/sw1), -7.f, 7.f);
  if (t<16){
    int bl = (int)rintf(b1[t]/sb1);
    WS_B1L(ws)[t] = bl;
    WS_B1F(ws)[t] = (float)bl;
  }
  for (int i=t;i<5120;i+=256){
    int chunk=i>>10, r=i&1023, ln=r>>4, j=r&15;
    int tap=2*chunk+(ln>>5), oc=ln&31;
    signed char v=0;
    if (tap<9) v=(signed char)clampf(rintf(w2[oc*144 + j*9 + tap]/sw2), -7.f, 7.f);
    WS_B2FR(ws)[i]=v;
  }
  for (int i=t;i<1024;i+=256){
    int ln=i>>4, j=i&15;
    int k=(ln>>5)*16+j, oc=ln&31;
    signed char v=0;
    if (k<9 && oc<16) v=(signed char)clampf(rintf(w1[oc*9+k]/sw1), -7.f, 7.f);
    WS_B1FR(ws)[i]=v;
  }
  float* mff = WS_MFF(ws);
  for (int i=t;i<15680;i+=256) mff[i] = clampf(rintf(wf[i]/swf), -7.f, 7.f);
  for (int i=t;i<50176;i+=256){
    int chunk=i>>10, r2=i&1023, ln=r2>>4, j=r2&15;
    int oc=ln&31, k=chunk*32+(ln>>5)*16+j;
    int cell=k>>5, ch=k&31;
    signed char v=0;
    if (oc<10) v=(signed char)clampf(rintf(wf[oc*1568 + ch*49 + cell]/swf), -7.f, 7.f);
    ((signed char*)WS_WFP(ws))[i]=v;
  }
}

// fallback scale kernels
template<bool FULLR>
__global__ void k_s1(const float* __restrict__ b2, char* ws){
  float* F=WS_F(ws); int* I=WS_I(ws);
  __shared__ int rA[256], rS[256];
  __shared__ float sh[4];
  int t=threadIdx.x;
  int amaxI, smaxI;
  if constexpr (FULLR){
    int a=0, s=INT_MIN;
    const int* ra=WS_RA1(ws); const int* rs=WS_RS1(ws);
    for (int i=t;i<6272;i+=256){ a=max(a,ra[i]); s=max(s,rs[i]); }
    rA[t]=a; rS[t]=s; __syncthreads();
    for (int st=128;st;st>>=1){ if (t<st){ rA[t]=max(rA[t],rA[t+st]); rS[t]=max(rS[t],rS[t+st]); } __syncthreads(); }
    amaxI=rA[0]; smaxI=rS[0];
  } else { amaxI=I[1]; smaxI=I[2]; }
  if (t==0){
    float sb1=F[3];
    float sy1 = fmaxf((sb1*(float)amaxI)/127.f, EPSQ);
    float mp  = sb1*(float)smaxI;
    float P1  = clampf(rintf(mp/sy1), 0.f, 127.f);
    float sr1 = fmaxf((sy1*P1)/15.f, EPSQ);
    float N1  = clampf(rintf((sy1*P1)/sr1), 0.f, 15.f);
    float sx2 = fmaxf((N1*sr1)/127.f, EPSQ);
    float sb2 = sx2*F[7];
    F[4]=sy1; F[5]=sr1; F[6]=sx2; F[8]=sb2;
    sh[0]=sy1; sh[1]=sr1; sh[2]=sx2; sh[3]=sb2;
  }
  __syncthreads();
  float sy1=sh[0], sr1=sh[1], sx2=sh[2], sb2=sh[3];
  int k = t-128;
  float n = (k>0) ? clampf(rintf((sy1*(float)k)/sr1), 0.f, 15.f) : 0.f;
  WS_Q2TAB(ws)[t] = (signed char)clampf(rintf((n*sr1)/sx2), -128.f, 127.f);
  if (t<32) WS_B2L(ws)[t] = (int)rintf(b2[t]/sb2);
}

// full path: fused s1 + q2big (256 blocks, deterministic redundant reduce)
__global__ void k_s1q2(const float* __restrict__ b2, char* ws){
  float* F=WS_F(ws);
  __shared__ int rA[256], rS[256];
  int t=threadIdx.x;
  int a=0, s=INT_MIN;
  const int* ra=WS_RA1(ws); const int* rs=WS_RS1(ws);
  for (int i=t;i<6272;i+=256){ a=max(a,ra[i]); s=max(s,rs[i]); }
  rA[t]=a; rS[t]=s; __syncthreads();
  for (int st=128;st;st>>=1){ if (t<st){ rA[t]=max(rA[t],rA[t+st]); rS[t]=max(rS[t],rS[t+st]); } __syncthreads(); }
  int amaxI=rA[0], smaxI=rS[0];
  float sb1=F[3];
  float sy1 = fmaxf((sb1*(float)amaxI)/127.f, EPSQ);
  float P1  = clampf(rintf((sb1*(float)smaxI)/sy1), 0.f, 127.f);
  float sr1 = fmaxf((sy1*P1)/15.f, EPSQ);
  float N1  = clampf(rintf((sy1*P1)/sr1), 0.f, 15.f);
  float sx2 = fmaxf((N1*sr1)/127.f, EPSQ);
  float sb2 = sx2*F[7];
  if (blockIdx.x==0){
    if (t==0){ F[4]=sy1; F[5]=sr1; F[6]=sx2; F[8]=sb2; }
    if (t<32) WS_B2L(ws)[t] = (int)rintf(b2[t]/sb2);
  }
  int idx = blockIdx.x*256 + t;
  int m = idx - 32768;
  float k1 = clampf(rintf((sb1*(float)m)/sy1), -128.f, 127.f);
  float n  = (k1>0.f) ? clampf(rintf((sy1*k1)/sr1), 0.f, 15.f) : 0.f;
  WS_Q2B(ws)[idx] = (signed char)clampf(rintf((n*sr1)/sx2), -128.f, 127.f);
}

template<bool FULLR>
__global__ void k_s2(const float* __restrict__ bf, char* ws){
  float* F=WS_F(ws); int* I=WS_I(ws);
  __shared__ int rA[256], rS[256];
  __shared__ float sh[4];
  int t=threadIdx.x;
  int amaxI, smaxI;
  if constexpr (FULLR){
    int a=0, s=INT_MIN;
    const int* ra=WS_RA2(ws); const int* rs=WS_RS2(ws);
    for (int i=t;i<2048;i+=256){ a=max(a,ra[i]); s=max(s,rs[i]); }
    rA[t]=a; rS[t]=s; __syncthreads();
    for (int st=128;st;st>>=1){ if (t<st){ rA[t]=max(rA[t],rA[t+st]); rS[t]=max(rS[t],rS[t+st]); } __syncthreads(); }
    amaxI=rA[0]; smaxI=rS[0];
  } else { amaxI=I[3]; smaxI=I[4]; }
  if (t==0){
    float sb2=F[8];
    float sy2 = fmaxf((sb2*(float)amaxI)/127.f, EPSQ);
    float mp  = sb2*(float)smaxI;
    float P2  = clampf(rintf(mp/sy2), 0.f, 127.f);
    float sr2 = fmaxf((sy2*P2)/15.f, EPSQ);
    float N2  = clampf(rintf((sy2*P2)/sr2), 0.f, 15.f);
    float sx3 = fmaxf((N2*sr2)/127.f, EPSQ);
    float sb3 = sx3*F[12];
    F[9]=sy2; F[10]=sr2; F[11]=sx3; F[13]=sb3;
    sh[0]=sy2; sh[1]=sr2; sh[2]=sx3; sh[3]=sb3;
  }
  __syncthreads();
  float sy2=sh[0], sr2=sh[1], sx3=sh[2], sb3=sh[3];
  int k = t-128;
  float n = (k>0) ? clampf(rintf((sy2*(float)k)/sr2), 0.f, 15.f) : 0.f;
  WS_Q3TAB(ws)[t] = (signed char)clampf(rintf((n*sr2)/sx3), -128.f, 127.f);
  if (t<16) WS_BFL(ws)[t] = (t<10) ? (int)rintf(bf[t]/sb3) : 0;
}

template<bool FULLR>
__global__ void k_s3(char* ws){
  float* F=WS_F(ws); int* I=WS_I(ws);
  __shared__ int rA[256];
  int t=threadIdx.x;
  int amaxI;
  if constexpr (FULLR){
    rA[t] = WS_RA3(ws)[t];
    __syncthreads();
    for (int st=128;st;st>>=1){ if (t<st) rA[t]=max(rA[t],rA[t+st]); __syncthreads(); }
    amaxI = rA[0];
  } else { amaxI = I[5]; }
  if (t==0) F[14] = fmaxf((F[13]*(float)amaxI)/127.f, EPSQ);
}

// ================= FULL PATH compute =================
// P2a: quantize x -> padded i8 [NB][30][32], zero borders. 1 thread = 1 u32 word.
__global__ void k_qx(const float* __restrict__ x, const char* __restrict__ ws,
                     signed char* __restrict__ qx){
  const float s0 = ((const float*)ws)[0];
  int id = blockIdx.x*256 + threadIdx.x;          // < NB*240
  int img = id/240, w = id - img*240;
  int r = w>>3, c4 = (w&7)<<2;
  const float* xi = x + img*784;
  unsigned out = 0;
#pragma unroll
  for (int j=0;j<4;j++){
    int c = c4+j;
    bool valid = (r>=1) && (r<=28) && (c>=1) && (c<=28);
    int q = 0;
    if (valid){
      float xv = xi[(r-1)*28 + (c-1)];
      q = (int)clampf(rintf(xv/s0), -128.f, 127.f);
    }
    out |= ((unsigned)(unsigned char)(signed char)q) << (8*j);
  }
  ((unsigned*)qx)[id] = out;
}

// P2b: conv1 via sdot4 + pool1 + per-block (amax,smax). 1 thread = 1 (img, pooled-cell).
__global__ __launch_bounds__(256) void k_conv1d(const signed char* __restrict__ qx,
                                                char* __restrict__ ws,
                                                short* __restrict__ i1p){
  const int t = threadIdx.x;
  const int id = blockIdx.x*256 + t;
  const int img = id/196, cell = id - img*196;
  const int py = cell/14, px = cell - py*14;
  const signed char* qb = qx + img*960 + (2*py)*32;
  const int pc0 = 2*px;
  const int al = pc0 & ~3, sh = (pc0&3)*8;
  unsigned wrd[4], whi[4];
#pragma unroll
  for (int rr=0; rr<4; rr++){
    unsigned lo = *(const unsigned*)(qb + rr*32 + al);
    unsigned hi = *(const unsigned*)(qb + rr*32 + al + 4);
    wrd[rr] = (unsigned)(((((unsigned long long)hi)<<32)|lo) >> sh);
    whi[rr] = wrd[rr] >> 8;
  }
  const unsigned* __restrict__ w1p = WS_W1P(ws);  // uniform -> s_load
  const int* __restrict__ b1l = WS_B1L(ws);
  int amax=0, smax=INT_MIN;
  short outv[16];
#pragma unroll
  for (int oc=0; oc<16; oc++){
    unsigned w0 = w1p[oc*3], w1 = w1p[oc*3+1], w2 = w1p[oc*3+2];
    int bl = b1l[oc];
    int a00 = dot4(wrd[2], w2, dot4(wrd[1], w1, dot4(wrd[0], w0, bl)));
    int a01 = dot4(whi[2], w2, dot4(whi[1], w1, dot4(whi[0], w0, bl)));
    int a10 = dot4(wrd[3], w2, dot4(wrd[2], w1, dot4(wrd[1], w0, bl)));
    int a11 = dot4(whi[3], w2, dot4(whi[2], w1, dot4(whi[1], w0, bl)));
    int mx = max(max(a00,a01), max(a10,a11));
    int ax = max(max(a00<0?-a00:a00, a01<0?-a01:a01), max(a10<0?-a10:a10, a11<0?-a11:a11));
    amax = max(amax, ax);
    smax = max(smax, mx);
    outv[oc] = (short)mx;
  }
  int4* dst = (int4*)(i1p + (size_t)id*16);
  dst[0] = *(const int4*)&outv[0];
  dst[1] = *(const int4*)&outv[8];
  reduce2_store(amax, smax, &WS_RA1(ws)[blockIdx.x], &WS_RS1(ws)[blockIdx.x]);
}

// P3: conv2 MFMA, pool-cell-grouped M-row permutation; requant via q2big table.
__global__ __launch_bounds__(256) void k_conv2r(char* __restrict__ ws,
                                                short* __restrict__ i1p,
                                                int* __restrict__ p2g){
  __shared__ __align__(16) signed char q2p4[4][4096];   // per-wave padded [16][16][16ch]
  const int t=threadIdx.x, lane=t&63, wid=t>>6;
  const int img = blockIdx.x*4 + wid;
  signed char* q2p = q2p4[wid];
  const signed char* __restrict__ q2b = WS_Q2B(ws);

#pragma unroll
  for (int k=0;k<8;k++) ((unsigned long long*)q2p)[lane + 64*k] = 0ULL;

  const unsigned* src = (const unsigned*)(i1p + (size_t)img*3136);
#pragma unroll
  for (int k=0;k<24;k++){
    int idx = lane + 64*k;
    unsigned wv = src[idx];
    int e0 = idx*2;
    int cellc = e0 >> 4, ch = e0 & 15;
    int pyc = cellc/14, pxc = cellc - pyc*14;
    int m0 = (int)(short)(wv & 0xFFFFu);
    int m1 = (int)(short)(wv >> 16);
    int b0 = (int)(unsigned char)q2b[m0+32768];
    int b1 = (int)(unsigned char)q2b[m1+32768];
    *(unsigned short*)(q2p + ((pyc+1)*16 + (pxc+1))*16 + ch) = (unsigned short)(b0 | (b1<<8));
  }
  if (lane < 32){
    int idx = 1536 + lane;
    unsigned wv = src[idx];
    int e0 = idx*2;
    int cellc = e0 >> 4, ch = e0 & 15;
    int pyc = cellc/14, pxc = cellc - pyc*14;
    int m0 = (int)(short)(wv & 0xFFFFu);
    int m1 = (int)(short)(wv >> 16);
    int b0 = (int)(unsigned char)q2b[m0+32768];
    int b1 = (int)(unsigned char)q2b[m1+32768];
    *(unsigned short*)(q2p + ((pyc+1)*16 + (pxc+1))*16 + ch) = (unsigned short)(b0 | (b1<<8));
  }

  i32x4 bfr[5];
  const i32x4* bg = (const i32x4*)WS_B2FR(ws);
#pragma unroll
  for (int c=0;c<5;c++) bfr[c] = bg[c*64+lane];
  const int col = lane&31, h = lane>>5;
  const int bias = WS_B2L(ws)[col];
  int amax2=0, smax2=INT_MIN;
  const int TOFF[9] = {0,1,2,16,17,18,32,33,34};
  int* dstb = p2g + (size_t)img*1568;

#pragma unroll
  for (int mt=0; mt<7; mt++){
    int m = mt*32 + col;
    int g = m>>2, sub = m&3;
    bool gv = g < 49;
    int py = (g*37)>>8;            // g/7, exact for g<56
    int px = g - py*7;
    int oy = 2*py + (sub>>1), ox = 2*px + (sub&1);
    int E0 = oy*16 + ox;
    i32x16 acc;
#pragma unroll
    for (int r=0;r<16;r++) acc[r] = bias;
#pragma unroll
    for (int c=0;c<5;c++){
      const int t0 = TOFF[2*c];
      const int t1 = (2*c+1<9) ? TOFF[2*c+1] : -1;
      int toff = h ? t1 : t0;
      int entry = (gv && toff>=0) ? (E0 + toff) : 0;   // entry 0 = zero border
      i32x4 a = *(const i32x4*)(q2p + entry*16);
      acc = __builtin_amdgcn_mfma_i32_32x32x32_i8(a, bfr[c], acc, 0,0,0);
    }
#pragma unroll
    for (int i=0;i<4;i++){
      int gg = mt*8 + 2*i + h;
      if (gg < 49){
        int v0=acc[4*i], v1=acc[4*i+1], v2=acc[4*i+2], v3=acc[4*i+3];
        int a0=v0<0?-v0:v0, a1=v1<0?-v1:v1, a2=v2<0?-v2:v2, a3=v3<0?-v3:v3;
        amax2 = max(amax2, max(max(a0,a1),max(a2,a3)));
        int mx = max(max(v0,v1),max(v2,v3));
        smax2 = max(smax2, mx);
        dstb[gg*32 + col] = mx;
      }
    }
  }
  reduce2_store(amax2, smax2, &WS_RA2(ws)[blockIdx.x], &WS_RS2(ws)[blockIdx.x]);
}

// P4: pooled-I2 -> q3 int8 levels (pure stream, 12544 blocks)
__global__ void k_rq2(const char* __restrict__ ws, const int* __restrict__ p2g,
                      signed char* __restrict__ q3g){
  const float* F = (const float*)ws;
  const float sb2 = F[8], sy2 = F[9];
  const signed char* q3t = WS_Q3TAB(ws);
  int id = blockIdx.x*256 + threadIdx.x;
  i32x4 m4 = ((const i32x4*)p2g)[id];
  unsigned out=0;
#pragma unroll
  for (int j=0;j<4;j++){
    float k2 = clampf(rintf((sb2*(float)m4[j])/sy2), -128.f, 127.f);
    out |= ((unsigned)(unsigned char)q3t[(int)k2+128]) << (8*j);
  }
  ((unsigned*)q3g)[id] = out;
}

// P5: fc as i8 MFMA GEMM, 256 blocks, K split across 4 waves (unrolled), LDS combine.
__global__ __launch_bounds__(256) void k_fc(char* __restrict__ ws,
                                            const signed char* __restrict__ q3g,
                                            int* __restrict__ i3out){
  __shared__ int part[3][16][64];
  int t=threadIdx.x, lane=t&63, wid=t>>6;
  int mt = blockIdx.x;              // 0..255
  const int col=lane&31, h=lane>>5;
  const signed char* A0 = q3g + (size_t)(mt*32 + col)*1568 + 16*h;
  const i32x4* wfp = (const i32x4*)WS_WFP(ws);
  i32x16 acc;
#pragma unroll
  for (int r=0;r<16;r++) acc[r]=0;
#pragma unroll
  for (int cc=0; cc<13; cc++){
    int c = wid + cc*4;
    if (c < 49){
      i32x4 a = *(const i32x4*)(A0 + c*32);
      i32x4 b = wfp[c*64 + lane];
      acc = __builtin_amdgcn_mfma_i32_32x32x32_i8(a, b, acc, 0,0,0);
    }
  }
  if (wid>0){
#pragma unroll
    for (int r=0;r<16;r++) part[wid-1][r][lane] = acc[r];
  }
  __syncthreads();
  if (wid==0){
    int bias = (col<10) ? WS_BFL(ws)[col] : 0;
    int am=0;
#pragma unroll
    for (int r=0;r<16;r++){
      int v = acc[r] + part[0][r][lane] + part[1][r][lane] + part[2][r][lane] + bias;
      int row=(r&3)+8*(r>>2)+4*h;
      int img = mt*32+row;
      if (col<10){
        i3out[img*10+col] = v;
        am = max(am, v<0?-v:v);
      }
    }
    am = wave_max_i(am);
    if (lane==0) WS_RA3(ws)[blockIdx.x] = am;
  }
}

// full-path output: inline RA3 reduce (deterministic, identical in every block)
__global__ void k_out2(char* __restrict__ ws, float* __restrict__ out){
  __shared__ int rA[256];
  int t=threadIdx.x;
  rA[t] = WS_RA3(ws)[t];
  __syncthreads();
  for (int st=128;st;st>>=1){ if (t<st) rA[t]=max(rA[t],rA[t+st]); __syncthreads(); }
  float sb3 = WS_F(ws)[13];
  float sy3 = fmaxf((sb3*(float)rA[0])/127.f, EPSQ);
  int i = blockIdx.x*256 + t;
  if (i < NB*10){
    int iv = ((const int*)out)[i];
    float y = sb3*(float)iv;
    float q = clampf(rintf(y/sy3), -128.f, 127.f);
    out[i] = q*sy3;
  }
}

// ================= FALLBACK (verified) =================
__global__ __launch_bounds__(256) void k_c1(const float* __restrict__ x, char* __restrict__ ws,
                                            short* __restrict__ i1p){
  constexpr int OFF_K0=0, OFF_A=960, OFF_I1=13760, OFF_B1=38848;
  __shared__ __align__(16) char arena[38912];
  signed char* k0b = (signed char*)(arena+OFF_K0);
  signed char* Abuf= (signed char*)(arena+OFF_A);
  short*       I1s = (short*)(arena+OFF_I1);
  int*         b1i = (int*)(arena+OFF_B1);

  const int tid=threadIdx.x, img=blockIdx.x;
  const int lane=tid&63, wid=tid>>6;
  const float s0 = WS_F(ws)[0];

  if (tid<16) b1i[tid]=WS_B1L(ws)[tid];
  for (int i=tid;i<240;i+=256) ((int*)k0b)[i]=0;
  for (int i=tid;i<3200;i+=256) ((int*)Abuf)[i]=0;
  __syncthreads();
  const float* xi = x + img*784;
  for (int i=tid;i<784;i+=256){
    int r=i/28, c=i-r*28;
    float v = clampf(rintf(xi[i]/s0), -128.f, 127.f);
    k0b[(r+1)*32 + (c+1)] = (signed char)v;
  }
  __syncthreads();
  for (int p=tid;p<784;p+=256){
    int oy=p/28, ox=p-oy*28;
    int base = oy*32+ox;
    int al = base & ~3, sh = (base&3)*8;
    unsigned l0a=*(const unsigned*)(k0b+al),    l1a=*(const unsigned*)(k0b+al+4);
    unsigned l0b=*(const unsigned*)(k0b+al+32), l1b=*(const unsigned*)(k0b+al+36);
    unsigned l0c=*(const unsigned*)(k0b+al+64), l1c=*(const unsigned*)(k0b+al+68);
    unsigned u0=(unsigned)(((((unsigned long long)l1a)<<32)|l0a)>>sh);
    unsigned u1=(unsigned)(((((unsigned long long)l1b)<<32)|l0b)>>sh);
    unsigned u2=(unsigned)(((((unsigned long long)l1c)<<32)|l0c)>>sh);
    i32x4 row;
    row[0]=(int)((u0&0xFFFFFFu)|(u1<<24));
    row[1]=(int)(((u1>>8)&0xFFFFu)|((u2&0xFFFFu)<<16));
    row[2]=(int)((u2>>16)&0xFFu);
    row[3]=0;
    *(i32x4*)(Abuf + p*16) = row;
  }
  __syncthreads();
  const i32x4 bfr = ((const i32x4*)WS_B1FR(ws))[lane];
  const int col=lane&31, h=lane>>5;
  const int bias=(col<16)? b1i[col] : 0;
  int amax=0, smax=INT_MIN;
  for (int mt=wid; mt<25; mt+=4){
    i32x4 a={0,0,0,0};
    if (h==0) a = *(const i32x4*)(Abuf + (mt*32+col)*16);
    i32x16 acc;
#pragma unroll
    for (int r=0;r<16;r++) acc[r]=bias;
    acc=__builtin_amdgcn_mfma_i32_32x32x32_i8(a,bfr,acc,0,0,0);
#pragma unroll
    for (int r=0;r<16;r++){
      int row=(r&3)+8*(r>>2)+4*h;
      int p=mt*32+row;
      if (p<784 && col<16){
        int v=acc[r];
        amax=max(amax,v<0?-v:v); smax=max(smax,v);
        I1s[p*16+col]=(short)v;
      }
    }
  }
  __syncthreads();
  for (int i=tid;i<3136;i+=256){
    int pp=i>>4, c=i&15, py=pp/14, px=pp-py*14;
    int p0=py*56+px*2;
    int m=max(max((int)I1s[p0*16+c],(int)I1s[(p0+1)*16+c]),
              max((int)I1s[(p0+28)*16+c],(int)I1s[(p0+29)*16+c]));
    i1p[(size_t)img*3136 + i]=(short)m;
  }
  reduce2_atomic(amax,smax,&WS_I(ws)[1],&WS_I(ws)[2]);
}

template<bool FIN>
__global__ __launch_bounds__(256) void k_c2(char* __restrict__ ws, const short* __restrict__ i1p,
                                            int* __restrict__ i3out){
  constexpr int OFF_Q2L=0, OFF_B2I=3136, OFF_Q2T=3264, OFF_N2=3520,
                OFF_Q3T=9792, OFF_BFS=10048, OFF_Q3F=10112, OFF_RED=16384;
  constexpr int ARENA = FIN ? 16544 : 3520;
  __shared__ __align__(16) char arena[ARENA];
  signed char* q2l=(signed char*)(arena+OFF_Q2L);
  int* b2li=(int*)(arena+OFF_B2I);
  signed char* q2t=(signed char*)(arena+OFF_Q2T);

  const int tid=threadIdx.x, img=blockIdx.x;
  const int lane=tid&63, wid=tid>>6;
  const float* F=WS_F(ws);
  const float sb1=F[3], sy1=F[4];

  q2t[tid]=WS_Q2TAB(ws)[tid];
  if (tid<32) b2li[tid]=WS_B2L(ws)[tid];
  if constexpr (FIN){
    ((signed char*)(arena+OFF_Q3T))[tid]=WS_Q3TAB(ws)[tid];
    if (tid<16) ((int*)(arena+OFF_BFS))[tid]=WS_BFL(ws)[tid];
  }
  __syncthreads();
  for (int i=tid;i<3136;i+=256){
    int m=(int)i1p[(size_t)img*3136+i];
    float k1=clampf(rintf((sb1*(float)m)/sy1),-128.f,127.f);
    q2l[i]=q2t[(int)k1+128];
  }
  __syncthreads();

  i32x4 bfr[5];
  {
    const i32x4* bg=(const i32x4*)WS_B2FR(ws);
#pragma unroll
    for (int c=0;c<5;c++) bfr[c]=bg[c*64+lane];
  }
  const int col=lane&31, h=lane>>5;
  const int bias=b2li[col];
  int amax2=0, smax2=INT_MIN;
  float sb2=0.f, sy2=0.f;
  signed char* n2buf=nullptr;
  if constexpr (FIN){ sb2=F[8]; sy2=F[9]; n2buf=(signed char*)(arena+OFF_N2); }

  for (int mt=wid; mt<7; mt+=4){
    const int p=mt*32+col;
    const bool pv=p<196;
    const int oy=p/14, ox=p-oy*14;
    i32x16 acc;
#pragma unroll
    for (int r=0;r<16;r++) acc[r]=bias;
#pragma unroll
    for (int c=0;c<5;c++){
      const int tap=2*c+h;
      i32x4 a={0,0,0,0};
      if (pv && tap<9){
        const int iy=oy+tap/3-1, ix=ox+tap-(tap/3)*3-1;
        if ((unsigned)iy<14u && (unsigned)ix<14u) a=*(const i32x4*)(q2l+(iy*14+ix)*16);
      }
      acc=__builtin_amdgcn_mfma_i32_32x32x32_i8(a,bfr[c],acc,0,0,0);
    }
#pragma unroll
    for (int r=0;r<16;r++){
      const int row=(r&3)+8*(r>>2)+4*h;
      const int pp=mt*32+row;
      if (pp<196){
        const int v=acc[r];
        if constexpr (!FIN){ amax2=max(amax2,v<0?-v:v); smax2=max(smax2,v); }
        else {
          n2buf[col*196+pp]=(signed char)clampf(rintf((sb2*(float)v)/sy2),-128.f,127.f);
        }
      }
    }
  }
  if constexpr (!FIN){
    reduce2_atomic(amax2,smax2,&WS_I(ws)[3],&WS_I(ws)[4]);
    return;
  } else {
    __syncthreads();
    signed char* q3t_s=(signed char*)(arena+OFF_Q3T);
    float* q3f=(float*)(arena+OFF_Q3F);
    for (int i=tid;i<1568;i+=256){
      int cch=i/49, s=i-cch*49, qy=s/7, qx=s-qy*7;
      int b=cch*196+qy*28+qx*2;
      int m=max(max((int)n2buf[b],(int)n2buf[b+1]),max((int)n2buf[b+14],(int)n2buf[b+15]));
      q3f[i]=(float)q3t_s[m+128];
    }
    __syncthreads();
    const float* mff=WS_MFF(ws);
    float a10[10];
#pragma unroll
    for (int o=0;o<10;o++) a10[o]=0.f;
    for (int k=tid;k<1568;k+=256){
      float qa=q3f[k];
#pragma unroll
      for (int o=0;o<10;o++) a10[o]=fmaf(qa,mff[o*1568+k],a10[o]);
    }
#pragma unroll
    for (int o=0;o<10;o++){
#pragma unroll
      for (int off=32;off;off>>=1) a10[o]+=__shfl_down(a10[o],off,64);
    }
    float* redf=(float*)(arena+OFF_RED);
    int* bfs=(int*)(arena+OFF_BFS);
    if (lane==0){
#pragma unroll
      for (int o=0;o<10;o++) redf[wid*10+o]=a10[o];
    }
    __syncthreads();
    if (tid<10){
      float s=redf[tid]+redf[10+tid]+redf[20+tid]+redf[30+tid];
      int I3v=(int)s+bfs[tid];
      i3out[img*10+tid]=I3v;
      redf[tid]=(float)(I3v<0?-I3v:I3v);
    }
    __syncthreads();
    if (tid==0){
      int m=0;
#pragma unroll
      for (int o=0;o<10;o++) m=max(m,(int)redf[o]);
      atomicMax(&WS_I(ws)[5],m);
    }
  }
}

__global__ void k_out(char* ws, float* __restrict__ out){
  float* F=WS_F(ws);
  float sb3=F[13], sy3=F[14];
  int i = blockIdx.x*blockDim.x + threadIdx.x;
  if (i < NB*10){
    int iv = ((const int*)out)[i];
    float y = sb3*(float)iv;
    float q = clampf(rintf(y/sy3), -128.f, 127.f);
    out[i] = q*sy3;
  }
}

extern "C" void kernel_launch(void* const* d_in, const int* in_sizes, int n_in,
                              void* d_out, int out_size, void* d_ws, size_t ws_size,
                              hipStream_t stream){
  const float* x  = (const float*)d_in[0];
  const float* w1 = (const float*)d_in[1];
  const float* b1 = (const float*)d_in[2];
  const float* w2 = (const float*)d_in[3];
  const float* b2 = (const float*)d_in[4];
  const float* wf = (const float*)d_in[5];
  const float* bf = (const float*)d_in[6];
  char* ws = (char*)d_ws;
  float* out = (float*)d_out;
  int* i3 = (int*)d_out;

  const size_t QX_SZ  = (size_t)NB*960;
  const size_t I1_SZ  = (size_t)NB*6272;
  const size_t Q3_SZ  = (size_t)NB*1568;
  const size_t needFull = (size_t)WS_BIG_OFF + QX_SZ + I1_SZ + Q3_SZ;

  if (ws_size >= needFull){
    signed char* qx  = (signed char*)(ws + WS_BIG_OFF);
    short*       i1p = (short*)(ws + WS_BIG_OFF + QX_SZ);
    int*         p2g = (int*)i1p;
    signed char* q3g = (signed char*)(ws + WS_BIG_OFF + QX_SZ + I1_SZ);
    k_absxw <<<dim3(2129), dim3(256), 0, stream>>>(x, w1, w2, wf, ws);
    k_scales<<<dim3(1), dim3(256), 0, stream>>>(w1, b1, ws);
    k_qx    <<<dim3(NB*240/256), dim3(256), 0, stream>>>(x, ws, qx);
    k_pack  <<<dim3(282), dim3(256), 0, stream>>>(w1, w2, wf, ws);
    k_conv1d<<<dim3(NB*196/256), dim3(256), 0, stream>>>(qx, ws, i1p);
    k_s1q2  <<<dim3(256), dim3(256), 0, stream>>>(b2, ws);
    k_conv2r<<<dim3(NB/4), dim3(256), 0, stream>>>(ws, i1p, p2g);
    k_s2<true><<<dim3(1), dim3(256), 0, stream>>>(bf, ws);
    k_rq2   <<<dim3(NB*1568/1024), dim3(256), 0, stream>>>(ws, p2g, q3g);
    k_fc    <<<dim3(256), dim3(256), 0, stream>>>(ws, q3g, i3);
    k_out2  <<<dim3((NB*10+255)/256), dim3(256), 0, stream>>>(ws, out);
  } else {
    short* i1p = (short*)(ws + WS_BIG_OFF);
    k_init<<<dim3(1), dim3(64), 0, stream>>>(ws);
    k_absx<<<dim3(2048), dim3(256), 0, stream>>>(x, ws);
    k_wq  <<<dim3(1), dim3(256), 0, stream>>>(w1, b1, w2, wf, ws);
    k_c1<<<dim3(NB), dim3(256), 0, stream>>>(x, ws, i1p);
    k_s1<false><<<dim3(1), dim3(256), 0, stream>>>(b2, ws);
    k_c2<false><<<dim3(NB), dim3(256), 0, stream>>>(ws, i1p, i3);
    k_s2<false><<<dim3(1), dim3(256), 0, stream>>>(bf, ws);
    k_c2<true ><<<dim3(NB), dim3(256), 0, stream>>>(ws, i1p, i3);
    k_s3<false><<<dim3(1), dim3(256), 0, stream>>>(ws);
    k_out<<<dim3((NB*10+255)/256), dim3(256), 0, stream>>>(ws, out);
  }
}